// Round 1
// baseline (59.442 us; speedup 1.0000x reference)
//
#include <hip/hip_runtime.h>

// YOLO loss on (B,7,7,30) fp32 pred/target -> scalar.
// Memory-bound: 2*B*49*30*4 bytes streamed once, ~150 FLOP/cell.

__device__ __forceinline__ float sq(float x) { return x * x; }

__device__ __forceinline__ void make_box(float cx, float cy, float w, float h,
                                         float jf, float kf, float b[4]) {
    float x = (cx + jf) / 7.0f;
    float y = (cy + kf) / 7.0f;
    b[0] = x - w * 0.5f;
    b[1] = y - h * 0.5f;
    b[2] = x + w * 0.5f;
    b[3] = y + h * 0.5f;
}

__device__ __forceinline__ float iou(const float a[4], const float b[4]) {
    float ix1 = fmaxf(a[0], b[0]);
    float iy1 = fmaxf(a[1], b[1]);
    float ix2 = fminf(a[2], b[2]);
    float iy2 = fminf(a[3], b[3]);
    float iw = fmaxf(ix2 - ix1, 0.0f);
    float ih = fmaxf(iy2 - iy1, 0.0f);
    float inter = iw * ih;
    float area_a = (a[2] - a[0]) * (a[3] - a[1]);
    float area_b = (b[2] - b[0]) * (b[3] - b[1]);
    return inter > 0.0f ? inter / (area_a + area_b - inter) : 0.0f;
}

__global__ void zero_out_kernel(float* out) { out[0] = 0.0f; }

__global__ __launch_bounds__(256) void yolo_loss_kernel(
    const float* __restrict__ pred, const float* __restrict__ targ,
    float* __restrict__ out, int ncells, float inv_b) {
    int cell = blockIdx.x * blockDim.x + threadIdx.x;

    float loss = 0.0f;
    if (cell < ncells) {
        const float* pp = pred + (size_t)cell * 30;
        const float* tt = targ + (size_t)cell * 30;

        float P[30], T[30];
#pragma unroll
        for (int i = 0; i < 15; ++i) {
            float2 v = *reinterpret_cast<const float2*>(pp + 2 * i);
            P[2 * i] = v.x;
            P[2 * i + 1] = v.y;
            float2 w = *reinterpret_cast<const float2*>(tt + 2 * i);
            T[2 * i] = w.x;
            T[2 * i + 1] = w.y;
        }

        int jc = (cell / 7) % 7;  // dim-1 index (row)
        int kc = cell % 7;        // dim-2 index (col)
        float jf = (float)jc, kf = (float)kc;

        float b1[4], b2[4], tb[4];
        make_box(P[0], P[1], P[2], P[3], jf, kf, b1);
        make_box(P[5], P[6], P[7], P[8], jf, kf, b2);
        make_box(T[0], T[1], T[2], T[3], jf, kf, tb);

        float i1 = iou(b1, tb);
        float i2 = iou(b2, tb);

        bool obj = T[4] > 0.0f;
        bool pick1 = i1 >= i2;

        float cls = 0.0f;
#pragma unroll
        for (int i = 10; i < 30; ++i) {
            float d = P[i] - T[i];
            cls += d * d;
        }

        float coo1 = 5.0f * (sq(P[0] - T[0]) + sq(P[1] - T[1]) +
                             sq(sqrtf(P[2]) - sqrtf(T[2])) +
                             sq(sqrtf(P[3]) - sqrtf(T[3]))) +
                     sq(P[4] - i1);
        float non1 = 0.5f * sq(P[4] - i2);

        float coo2 = 5.0f * (sq(P[5] - T[5]) + sq(P[6] - T[6]) +
                             sq(sqrtf(P[7]) - sqrtf(T[7])) +
                             sq(sqrtf(P[8]) - sqrtf(T[8]))) +
                     sq(P[9] - i2);
        float non2 = 0.5f * sq(P[9] - i1);

        float noobj = 0.5f * (P[4] * P[4] + P[9] * P[9]);

        float resp = pick1 ? (coo1 + non1) : (coo2 + non2);
        loss = obj ? (resp + cls) : noobj;
    }

    // wave-64 reduction
#pragma unroll
    for (int off = 32; off > 0; off >>= 1) loss += __shfl_down(loss, off);

    __shared__ float wsum[4];  // 256 threads / 64 lanes
    int wid = threadIdx.x >> 6;
    int lane = threadIdx.x & 63;
    if (lane == 0) wsum[wid] = loss;
    __syncthreads();

    if (threadIdx.x == 0) {
        float s = wsum[0] + wsum[1] + wsum[2] + wsum[3];
        atomicAdd(out, s * inv_b);
    }
}

extern "C" void kernel_launch(void* const* d_in, const int* in_sizes, int n_in,
                              void* d_out, int out_size, void* d_ws, size_t ws_size,
                              hipStream_t stream) {
    const float* pred = (const float*)d_in[0];
    const float* targ = (const float*)d_in[1];
    float* out = (float*)d_out;

    int ncells = in_sizes[0] / 30;          // B*7*7
    int batch = ncells / 49;                // B
    float inv_b = 1.0f / (float)batch;

    zero_out_kernel<<<1, 1, 0, stream>>>(out);

    int block = 256;
    int grid = (ncells + block - 1) / block;
    yolo_loss_kernel<<<grid, block, 0, stream>>>(pred, targ, out, ncells, inv_b);
}